// Round 8
// baseline (339.067 us; speedup 1.0000x reference)
//
#include <hip/hip_runtime.h>

typedef unsigned short u16;
typedef unsigned int   u32;
typedef __bf16   bf16x8 __attribute__((ext_vector_type(8)));
typedef float    f32x4  __attribute__((ext_vector_type(4)));
typedef u16      u16x4  __attribute__((ext_vector_type(4)));
typedef u16      u16x8  __attribute__((ext_vector_type(8)));
typedef u32      u32x2  __attribute__((ext_vector_type(2)));
typedef u32      u32x4  __attribute__((ext_vector_type(4)));

#if __has_builtin(__builtin_amdgcn_exp2f)
#define EXP2(x) __builtin_amdgcn_exp2f(x)
#else
#define EXP2(x) exp2f(x)
#endif

// fp32 -> bf16 round-to-nearest-even
__device__ __forceinline__ u16 f2bf(float f) {
    unsigned u = __float_as_uint(f);
    u += 0x7FFFu + ((u >> 16) & 1u);
    return (u16)(u >> 16);
}

__device__ __forceinline__ u32 pack_bf16(float a, float b) {
#if __has_builtin(__builtin_amdgcn_cvt_pk_bf16_f32)
    typedef __bf16 bf16x2 __attribute__((ext_vector_type(2)));
    bf16x2 r = __builtin_amdgcn_cvt_pk_bf16_f32(a, b);
    return __builtin_bit_cast(u32, r);
#else
    return (u32)f2bf(a) | ((u32)f2bf(b) << 16);
#endif
}

// async global->LDS, 16 bytes/lane. LDS dest = wave-uniform base + lane*16.
__device__ __forceinline__ void async_copy16(const u16* g, u16* l) {
    __builtin_amdgcn_global_load_lds(
        (const __attribute__((address_space(1))) unsigned*)g,
        (__attribute__((address_space(3))) unsigned*)l, 16, 0, 0);
}

__device__ __forceinline__ bf16x8 lds_frag(const u16* p) {
    return *(const bf16x8*)p;
}

// ---------------------------------------------------------------------------
// Fused prep: blocks [0,768) transpose Wqkv, [768,1024) transpose Wout,
// [1024,5120) convert x to bf16 (16 elems/thread).
__global__ __launch_bounds__(256) void prep(const float* __restrict__ x,
                                            const float* __restrict__ Wqkv,
                                            const float* __restrict__ Wout,
                                            u16* __restrict__ xb,
                                            u16* __restrict__ wqkv_t,
                                            u16* __restrict__ wout_t) {
    __shared__ u16 t[64 * 72];
    const int bid = blockIdx.x;
    const int tid = threadIdx.x;

    if (bid >= 1024) {
        size_t i = ((size_t)(bid - 1024) * 256 + tid) * 8;
        float4 v0 = *(const float4*)(x + i);
        float4 v1 = *(const float4*)(x + i + 4);
        u16x8 o = { f2bf(v0.x), f2bf(v0.y), f2bf(v0.z), f2bf(v0.w),
                    f2bf(v1.x), f2bf(v1.y), f2bf(v1.z), f2bf(v1.w) };
        *(u16x8*)(xb + i) = o;
        return;
    }

    const float* W;  u16* Wt;  int Kd, Nd, n0, k0;
    if (bid < 768) { W = Wqkv; Wt = wqkv_t; Kd = 1024; Nd = 3072;
                     n0 = (bid % 48) * 64; k0 = (bid / 48) * 64; }
    else           { W = Wout; Wt = wout_t; Kd = 1024; Nd = 1024;
                     n0 = ((bid - 768) % 16) * 64; k0 = ((bid - 768) / 16) * 64; }
#pragma unroll
    for (int i = 0; i < 4; ++i) {
        int lin = i * 256 + tid;
        int kr = lin >> 4, nc = (lin & 15) << 2;
        float4 v = *(const float4*)(W + (size_t)(k0 + kr) * Nd + n0 + nc);
        u16x4 o = { f2bf(v.x), f2bf(v.y), f2bf(v.z), f2bf(v.w) };
        *(u16x4*)&t[kr * 72 + nc] = o;
    }
    __syncthreads();
#pragma unroll
    for (int i = 0; i < 2; ++i) {
        int lin = i * 256 + tid;
        int nr = lin >> 3, kc = (lin & 7) << 3;
        u16x8 o;
#pragma unroll
        for (int jj = 0; jj < 8; ++jj) o[jj] = t[(kc + jj) * 72 + nr];
        *(u16x8*)(Wt + (size_t)(n0 + nr) * Kd + k0 + kc) = o;
    }
}

// ---------------------------------------------------------------------------
// QKV gemm: A via LDS dbuf (swizzled, conflict-free); B DIRECT FROM GLOBAL
// (L2-hot weights, register-prefetched one iter ahead — no barrier dep, so
// the loads pipeline across K-iterations). Halves LDS traffic vs R7.
// 8x8-block supertile swizzle: each XCD owns one bx column -> B-slice 256KB
// reused 8x from its L2, A working set 2MB.
__global__ __launch_bounds__(256) void gemm_qkv(const u16* __restrict__ A,
                                                const u16* __restrict__ Bt,
                                                u16* __restrict__ outb) {
    const int K = 1024;
    __shared__ u16 As[2][128 * 32];
    const int tid = threadIdx.x;
    const int lane = tid & 63;
    const int wv = tid >> 6;
    const int wr = (wv >> 1) * 64;
    const int wc = (wv & 1) * 64;
    const int qd = lane >> 4;
    const int c  = lane & 15;

    // supertile swizzle: 24x64 block grid, supertiles of 8x8
    const int flat = blockIdx.x;
    const int s = flat >> 6, t = flat & 63;
    const int bx = (t & 7) + 8 * (s % 3);
    const int by = (t >> 3) + 8 * (s / 3);
    const int m0 = by * 128;
    const int n0 = bx * 128;

    const int srow = tid >> 2;
    const int sg = ((tid & 3) ^ ((srow >> 1) & 3)) << 3;   // swizzled source chunk

    const u16* Ag0 = A + (size_t)(m0 +      srow) * K + sg;
    const u16* Ag1 = A + (size_t)(m0 + 64 + srow) * K + sg;

    const u32 fsw = (qd ^ ((c >> 1) & 3)) << 3;            // swizzled frag chunk
    const u32 a_off = (wr + c) * 32 + fsw;                 // + i*512

    // B direct-global bases: lane (c,qd) reads 16B at row n0+wc+j*16+c
    const u16* bg[4];
#pragma unroll
    for (int j = 0; j < 4; ++j)
        bg[j] = Bt + (size_t)(n0 + wc + j * 16 + c) * K + qd * 8;

    f32x4 acc[4][4] = {};

    async_copy16(Ag0, &As[0][tid * 8]);
    async_copy16(Ag1, &As[0][2048 + tid * 8]);
    bf16x8 bcur[4], bnxt[4];
#pragma unroll
    for (int j = 0; j < 4; ++j) bcur[j] = *(const bf16x8*)(bg[j]);

    int p = 0;
    for (int k0 = 0; k0 < K; k0 += 32) {
        __syncthreads();
        if (k0 + 32 < K) {
            const int np = p ^ 1;
            async_copy16(Ag0 + k0 + 32, &As[np][tid * 8]);
            async_copy16(Ag1 + k0 + 32, &As[np][2048 + tid * 8]);
#pragma unroll
            for (int j = 0; j < 4; ++j) bnxt[j] = *(const bf16x8*)(bg[j] + k0 + 32);
        }
        bf16x8 af[4];
#pragma unroll
        for (int i = 0; i < 4; ++i) af[i] = lds_frag(&As[p][a_off + i * 512]);
#pragma unroll
        for (int i = 0; i < 4; ++i)
#pragma unroll
            for (int j = 0; j < 4; ++j)
                acc[i][j] = __builtin_amdgcn_mfma_f32_16x16x32_bf16(af[i], bcur[j], acc[i][j], 0, 0, 0);
#pragma unroll
        for (int j = 0; j < 4; ++j) bcur[j] = bnxt[j];
        p ^= 1;
    }

    // C/D layout: col = lane&15, row = (lane>>4)*4 + reg
#pragma unroll
    for (int i = 0; i < 4; ++i)
#pragma unroll
        for (int j = 0; j < 4; ++j) {
            int n = n0 + wc + j * 16 + c;
            int which = n >> 10, h = (n >> 6) & 15, kd = n & 63;
            int m_base = m0 + wr + i * 16 + qd * 4;
            int b = m_base >> 11, l0 = m_base & 2047;
            int bh = b * 16 + h;
            if (which == 2) {
                u32x2 o2;
                o2[0] = pack_bf16(acc[i][j][0], acc[i][j][1]);
                o2[1] = pack_bf16(acc[i][j][2], acc[i][j][3]);
                *(u32x2*)(outb + (size_t)(128 + bh) * 131072 + (size_t)kd * 2048 + l0) = o2;
            } else if (which == 0) {
#pragma unroll
                for (int r = 0; r < 4; ++r)
                    outb[(size_t)bh * 131072 + (size_t)(l0 + r) * 64 + kd] =
                        f2bf(acc[i][j][r] * 0.1803368801f);   // 0.125*log2(e)
            } else {
#pragma unroll
                for (int r = 0; r < 4; ++r)
                    outb[(size_t)(64 + bh) * 131072 + (size_t)(l0 + r) * 64 + kd] =
                        f2bf(acc[i][j][r]);
            }
        }
}

// ---------------------------------------------------------------------------
// Output gemm: 64x128 tile, A via LDS dbuf, B direct from global (Wout 2MB,
// L2-resident). Grid 1024 blocks, supertile swizzle (XCD owns one bx).
__global__ __launch_bounds__(256) void gemm_out(const u16* __restrict__ A,
                                                const u16* __restrict__ Bt,
                                                float* __restrict__ outf) {
    const int K = 1024, N = 1024;
    __shared__ u16 As[2][64 * 32];
    const int tid = threadIdx.x;
    const int lane = tid & 63;
    const int wv = tid >> 6;
    const int wr = (wv >> 1) * 32;
    const int wc = (wv & 1) * 64;
    const int qd = lane >> 4;
    const int c  = lane & 15;

    const int flat = blockIdx.x;
    const int s = flat >> 6, t = flat & 63;
    const int bx = t & 7;
    const int by = (t >> 3) + 8 * s;
    const int m0 = by * 64;
    const int n0 = bx * 128;

    const int srow = tid >> 2;
    const int sg = ((tid & 3) ^ ((srow >> 1) & 3)) << 3;

    const u16* Ag0 = A + (size_t)(m0 + srow) * K + sg;

    const u32 fsw = (qd ^ ((c >> 1) & 3)) << 3;
    const u32 a_off = (wr + c) * 32 + fsw;

    const u16* bg[4];
#pragma unroll
    for (int j = 0; j < 4; ++j)
        bg[j] = Bt + (size_t)(n0 + wc + j * 16 + c) * K + qd * 8;

    f32x4 acc[2][4] = {};

    async_copy16(Ag0, &As[0][tid * 8]);
    bf16x8 bcur[4], bnxt[4];
#pragma unroll
    for (int j = 0; j < 4; ++j) bcur[j] = *(const bf16x8*)(bg[j]);

    int p = 0;
    for (int k0 = 0; k0 < K; k0 += 32) {
        __syncthreads();
        if (k0 + 32 < K) {
            const int np = p ^ 1;
            async_copy16(Ag0 + k0 + 32, &As[np][tid * 8]);
#pragma unroll
            for (int j = 0; j < 4; ++j) bnxt[j] = *(const bf16x8*)(bg[j] + k0 + 32);
        }
        bf16x8 af[2];
#pragma unroll
        for (int i = 0; i < 2; ++i) af[i] = lds_frag(&As[p][a_off + i * 512]);
#pragma unroll
        for (int i = 0; i < 2; ++i)
#pragma unroll
            for (int j = 0; j < 4; ++j)
                acc[i][j] = __builtin_amdgcn_mfma_f32_16x16x32_bf16(af[i], bcur[j], acc[i][j], 0, 0, 0);
#pragma unroll
        for (int j = 0; j < 4; ++j) bcur[j] = bnxt[j];
        p ^= 1;
    }

#pragma unroll
    for (int i = 0; i < 2; ++i)
#pragma unroll
        for (int j = 0; j < 4; ++j)
#pragma unroll
            for (int r = 0; r < 4; ++r) {
                int m = m0 + wr + i * 16 + qd * 4 + r;
                int n = n0 + wc + j * 16 + c;
                outf[(size_t)m * N + n] = acc[i][j][r];
            }
}

// ---------------------------------------------------------------------------
// Flash attention, causal, S^T form, double-buffered K/V, 2 q-frags/wave,
// zero-offset softmax exp2(s)/sum (s is O(1) in log2 domain; fp32-safe).
// LDS: Ks dbuf 32K + Vt dbuf 32K + Ps 16K = 81920 B -> exactly 2 blocks/CU.
__global__ __launch_bounds__(256, 2) void attn_kernel(const u16* __restrict__ qkv,
                                                      u16* __restrict__ att) {
    __shared__ u16 Ks[2][128 * 64];   // [key][kd], 16B-chunk XOR swizzled
    __shared__ u16 Vt[2][64 * 128];   // [kd][key], 16B-chunk XOR swizzled
    __shared__ u16 Ps[4][16 * 128];   // per-wave P^T, 16B-chunk XOR swizzled

    const int tid = threadIdx.x;
    const int lane = tid & 63;
    const int w = tid >> 6;
    const int qd = lane >> 4;
    const int c = lane & 15;

    // XCD swizzle: flat%8 == bh%8 -> one bh's K/V stays in one XCD L2
    const int flat = blockIdx.x + 8 * blockIdx.y;
    const int bh = (flat & 7) + 8 * ((flat >> 3) & 7);
    const int bx = flat >> 6;
    const int b = bh >> 4, h = bh & 15;

    const u16* Qg = qkv + (size_t)bh * 131072;
    const u16* Kg = qkv + (size_t)(64 + bh) * 131072;
    const u16* Vg = qkv + (size_t)(128 + bh) * 131072;   // [kd][2048]

    u32 k_go[4], v_go[4], s_lo[4];
#pragma unroll
    for (int it = 0; it < 4; ++it) {
        int lin = it * 256 + tid;
        int krw = lin >> 3, kch = lin & 7;
        k_go[it] = krw * 64 + ((kch ^ (krw & 7)) << 3);
        int vrw = lin >> 4, vch = lin & 15;
        v_go[it] = vrw * 2048 + ((vch ^ (vrw & 15)) << 3);
        s_lo[it] = lin * 8;
    }

    u32 kf_off[2];
#pragma unroll
    for (int ks = 0; ks < 2; ++ks)
        kf_off[ks] = c * 64 + (((ks * 4 + qd) ^ (c & 7)) << 3);
    u32 vf_off[4];
#pragma unroll
    for (int kc = 0; kc < 4; ++kc)
        vf_off[kc] = c * 128 + (((kc * 4 + qd) ^ c) << 3);
    u16* psw = &Ps[w][c * 128 + (qd & 1) * 4];
    const u16* psr = &Ps[w][c * 128];

#pragma unroll
    for (int seg = 0; seg < 2; ++seg) {
        const int qt = seg ? (15 - bx) : bx;
        const int qa_row = qt * 128 + w * 32 + c;        // frag a
        const int qb_row = qa_row + 16;                  // frag b

        bf16x8 qa[2], qb[2];
#pragma unroll
        for (int ks = 0; ks < 2; ++ks) {
            qa[ks] = *(const bf16x8*)(Qg + (size_t)qa_row * 64 + ks * 32 + qd * 8);
            qb[ks] = *(const bf16x8*)(Qg + (size_t)qb_row * 64 + ks * 32 + qd * 8);
        }

        f32x4 acca[4] = {}, accb[4] = {};
        float ra = 0.0f, rb = 0.0f;      // per-lane partial row-sums

        const int nkt = qt + 1;
        int p = 0;
        for (int kt = 0; kt < nkt; ++kt) {
            __syncthreads();
            if (kt == 0) {
#pragma unroll
                for (int it = 0; it < 4; ++it) {
                    async_copy16(Kg + (size_t)kt * 8192 + k_go[it], &Ks[0][s_lo[it]]);
                    async_copy16(Vg + (size_t)kt * 128  + v_go[it], &Vt[0][s_lo[it]]);
                }
                __syncthreads();
            }
            if (kt + 1 < nkt) {
                const int nt = kt + 1, np = p ^ 1;
#pragma unroll
                for (int it = 0; it < 4; ++it) {
                    async_copy16(Kg + (size_t)nt * 8192 + k_go[it], &Ks[np][s_lo[it]]);
                    async_copy16(Vg + (size_t)nt * 128  + v_go[it], &Vt[np][s_lo[it]]);
                }
            }

            const u16* ksb = Ks[p];
            const u16* vtb = Vt[p];

            // S^T = K Q^T, both q-frags share each K fragment
            f32x4 sa[8] = {}, sb[8] = {};
#pragma unroll
            for (int ks = 0; ks < 2; ++ks) {
                const u16* kp = ksb + kf_off[ks];
#pragma unroll
                for (int f = 0; f < 8; ++f) {
                    bf16x8 kf = lds_frag(kp + f * 1024);
                    sa[f] = __builtin_amdgcn_mfma_f32_16x16x32_bf16(kf, qa[ks], sa[f], 0, 0, 0);
                    sb[f] = __builtin_amdgcn_mfma_f32_16x16x32_bf16(kf, qb[ks], sb[f], 0, 0, 0);
                }
            }

            // causal mask — diagonal tile only (-3e38 -> exp2 -> 0)
            if (kt == qt) {
#pragma unroll
                for (int f = 0; f < 8; ++f)
#pragma unroll
                    for (int r = 0; r < 4; ++r) {
                        int key = kt * 128 + f * 16 + qd * 4 + r;
                        if (key > qa_row) sa[f][r] = -3e38f;
                        if (key > qb_row) sb[f][r] = -3e38f;
                    }
            }

            // zero-offset exp2; per-lane sums (no cross-lane on critical path)
#pragma unroll
            for (int f = 0; f < 8; ++f)
#pragma unroll
                for (int r = 0; r < 4; ++r) {
                    float pa = EXP2(sa[f][r]);
                    float pb = EXP2(sb[f][r]);
                    sa[f][r] = pa; sb[f][r] = pb;
                    ra += pa; rb += pb;
                }

            // P^T transpose via per-wave swizzled LDS round-trip (a, then b)
            u32x4 pfa[4], pfb[4];
#pragma unroll
            for (int f = 0; f < 8; ++f) {
                u32x2 pw;
                pw[0] = pack_bf16(sa[f][0], sa[f][1]);
                pw[1] = pack_bf16(sa[f][2], sa[f][3]);
                *(u32x2*)(psw + (((f * 2 + (qd >> 1)) ^ c) << 3)) = pw;
            }
#pragma unroll
            for (int kc = 0; kc < 4; ++kc)
                pfa[kc] = *(const u32x4*)(psr + (((kc * 4 + qd) ^ c) << 3));
#pragma unroll
            for (int f = 0; f < 8; ++f) {
                u32x2 pw;
                pw[0] = pack_bf16(sb[f][0], sb[f][1]);
                pw[1] = pack_bf16(sb[f][2], sb[f][3]);
                *(u32x2*)(psw + (((f * 2 + (qd >> 1)) ^ c) << 3)) = pw;
            }
#pragma unroll
            for (int kc = 0; kc < 4; ++kc)
                pfb[kc] = *(const u32x4*)(psr + (((kc * 4 + qd) ^ c) << 3));

            // O^T += V^T P^T; V fragments shared by both q-frags
#pragma unroll
            for (int kc = 0; kc < 4; ++kc) {
                const u16* vp = vtb + vf_off[kc];
                bf16x8 pa = __builtin_bit_cast(bf16x8, pfa[kc]);
                bf16x8 pb = __builtin_bit_cast(bf16x8, pfb[kc]);
#pragma unroll
                for (int jo = 0; jo < 4; ++jo) {
                    bf16x8 vf = lds_frag(vp + jo * 2048);
                    acca[jo] = __builtin_amdgcn_mfma_f32_16x16x32_bf16(vf, pa, acca[jo], 0, 0, 0);
                    accb[jo] = __builtin_amdgcn_mfma_f32_16x16x32_bf16(vf, pb, accb[jo], 0, 0, 0);
                }
            }
            p ^= 1;
        }

        // epilogue: reduce row-sums across the 4 quad-groups, then scale
        ra += __shfl_xor(ra, 16, 64);
        ra += __shfl_xor(ra, 32, 64);
        rb += __shfl_xor(rb, 16, 64);
        rb += __shfl_xor(rb, 32, 64);
        float ia = __builtin_amdgcn_rcpf(ra), ib = __builtin_amdgcn_rcpf(rb);
        u16* ar = att + ((size_t)b * 2048 + qa_row) * 1024 + h * 64;
        u16* br = att + ((size_t)b * 2048 + qb_row) * 1024 + h * 64;
#pragma unroll
        for (int jo = 0; jo < 4; ++jo) {
            u32x2 oa, ob;
            oa[0] = pack_bf16(acca[jo][0] * ia, acca[jo][1] * ia);
            oa[1] = pack_bf16(acca[jo][2] * ia, acca[jo][3] * ia);
            ob[0] = pack_bf16(accb[jo][0] * ib, accb[jo][1] * ib);
            ob[1] = pack_bf16(accb[jo][2] * ib, accb[jo][3] * ib);
            *(u32x2*)(ar + jo * 16 + qd * 4) = oa;
            *(u32x2*)(br + jo * 16 + qd * 4) = ob;
        }
    }
}

// ---------------------------------------------------------------------------
extern "C" void kernel_launch(void* const* d_in, const int* in_sizes, int n_in,
                              void* d_out, int out_size, void* d_ws, size_t ws_size,
                              hipStream_t stream) {
    const float* x    = (const float*)d_in[0];   // [4,2048,1024]
    const float* Wqkv = (const float*)d_in[1];   // [1024,3072]
    const float* Wout = (const float*)d_in[2];   // [1024,1024]
    float* out = (float*)d_out;                  // [4,2048,1024] fp32

    char* ws = (char*)d_ws;
    u16* x_bf   = (u16*)(ws);                    // 16 MB
    u16* wqkv_t = (u16*)(ws + 16777216);         // 6 MB   [3072][1024]
    u16* wout_t = (u16*)(ws + 23068672);         // 2 MB   [1024][1024]
    u16* qkv_h  = (u16*)(ws + 25165824);         // 48 MB  Q,K [bh][l][64], V^T [bh][kd][2048]
    u16* att    = (u16*)(ws + 75497472);         // 16 MB  [4][2048][1024]

    prep<<<dim3(5120), dim3(256), 0, stream>>>(x, Wqkv, Wout, x_bf, wqkv_t, wout_t);
    gemm_qkv<<<dim3(1536), dim3(256), 0, stream>>>(x_bf, wqkv_t, qkv_h);
    attn_kernel<<<dim3(8, 64), dim3(256), 0, stream>>>(qkv_h, att);
    gemm_out<<<dim3(1024), dim3(256), 0, stream>>>(att, wout_t, out);
}